// Round 4
// baseline (623.291 us; speedup 1.0000x reference)
//
#include <hip/hip_runtime.h>
#include <hip/hip_fp16.h>

#define N_NODES 100000
#define N_EDGES 1600000
#define IN_DIM 128
#define HIDDEN 16
#define OUT_DIM 40
#define QMAXF 255.0f

#define NB 512            // buckets
#define RPB 196           // rows per bucket (512*196 = 100352 >= N_NODES)
#define NB_USED 511       // max bucket index = 99999/196 = 510
#define BUCKET_CAP 4096   // mean fill 3136, sigma ~56 -> 17 sigma headroom
#define TILE 4096         // edges per bin block
#define EPT 16            // edges per thread in k_bin (TILE/256)
#define NBLK_BIN ((N_EDGES + TILE - 1) / TILE)  // 391

__device__ __forceinline__ float qd_one(float x, float noise, float rmin,
                                        float rscale, float inv) {
    float q = rintf((x - rmin) * rscale + noise - 0.5f);
    q = fminf(fmaxf(q, 0.0f), QMAXF);
    return q * inv + rmin;
}

// ---------------- edge binning (once; reused by all 3 SpMMs) ----------------

__global__ __launch_bounds__(512) void k_initcur(int* __restrict__ cursor) {
    const int i = threadIdx.x;
    if (i < NB) cursor[i] = i * BUCKET_CAP;
}

// One pass: per-block LDS histogram -> block counting-sort into LDS stage ->
// bucket-contiguous global writes (runs ~64B). cursor[b] ends at segment end.
__global__ __launch_bounds__(256) void k_bin(
    const int* __restrict__ row, const int* __restrict__ col,
    const float* __restrict__ vals, int* __restrict__ cursor,
    int2* __restrict__ es) {
    __shared__ int hist[NB];
    __shared__ int psum[256];
    __shared__ int lofs[NB];
    __shared__ int lcur[NB];
    __shared__ int gbase[NB];
    __shared__ int2 stage[TILE];
    __shared__ int dsti[TILE];

    const int tid = threadIdx.x;
    for (int i = tid; i < NB; i += 256) hist[i] = 0;
    __syncthreads();

    int bk[EPT];
    int2 ev[EPT];
    const int e0 = blockIdx.x * TILE;
#pragma unroll
    for (int k = 0; k < EPT; ++k) {
        const int e = e0 + k * 256 + tid;
        if (e < N_EDGES) {
            const int r = row[e];
            const int b = r / RPB;
            bk[k] = b;
            ev[k] = make_int2(col[e] | ((r - b * RPB) << 17),
                              __float_as_int(vals[e]));
            atomicAdd(&hist[b], 1);
        } else {
            bk[k] = -1;
        }
    }
    __syncthreads();

    // scan 512 hist entries with 256 threads (2 buckets/thread)
    const int h0 = hist[2 * tid], h1 = hist[2 * tid + 1];
    psum[tid] = h0 + h1;
    __syncthreads();
    for (int off = 1; off < 256; off <<= 1) {
        int x = (tid >= off) ? psum[tid - off] : 0;
        __syncthreads();
        psum[tid] += x;
        __syncthreads();
    }
    const int excl = (tid == 0) ? 0 : psum[tid - 1];
    lofs[2 * tid] = excl;
    lofs[2 * tid + 1] = excl + h0;
    lcur[2 * tid] = excl;
    lcur[2 * tid + 1] = excl + h0;
    if (h0) gbase[2 * tid] = atomicAdd(&cursor[2 * tid], h0);
    if (h1) gbase[2 * tid + 1] = atomicAdd(&cursor[2 * tid + 1], h1);
    __syncthreads();

#pragma unroll
    for (int k = 0; k < EPT; ++k) {
        if (bk[k] >= 0) {
            const int b = bk[k];
            const int lp = atomicAdd(&lcur[b], 1);
            stage[lp] = ev[k];
            dsti[lp] = gbase[b] + (lp - lofs[b]);
        }
    }
    __syncthreads();

    const int S = psum[255];
    for (int i = tid; i < S; i += 256) es[dsti[i]] = stage[i];
}

// SpMM: one block per bucket; fp32 accumulator rows in LDS; fp16 y gathers.
__global__ __launch_bounds__(256) void k_spmm_bin(
    const int* __restrict__ cursor, const int2* __restrict__ es,
    const __half* __restrict__ y, float* __restrict__ z) {
    __shared__ float acc[RPB * HIDDEN];  // 12.5 KB
    const int b = blockIdx.x;
    for (int i = threadIdx.x; i < RPB * HIDDEN; i += 256) acc[i] = 0.0f;
    __syncthreads();

    const int start = b * BUCKET_CAP;
    const int end = cursor[b];
    const int c = threadIdx.x & 3;
    for (int j = start + (threadIdx.x >> 2); j < end; j += 64) {
        const int2 e = es[j];
        const float v = __int_as_float(e.y);
        const int cl = e.x & 0x1FFFF;
        const int rr = e.x >> 17;
        const uint2 hv = *(const uint2*)(y + cl * HIDDEN + c * 4);
        const float2 f01 = __half22float2(*(const __half2*)&hv.x);
        const float2 f23 = __half22float2(*(const __half2*)&hv.y);
        float* ap = &acc[rr * HIDDEN + c * 4];
        atomicAdd(ap + 0, v * f01.x);
        atomicAdd(ap + 1, v * f01.y);
        atomicAdd(ap + 2, v * f23.x);
        atomicAdd(ap + 3, v * f23.y);
    }
    __syncthreads();

    const int rowBase = b * RPB;
    const int n = (N_NODES - rowBase < RPB ? N_NODES - rowBase : RPB) * HIDDEN;
    float* zb = z + (size_t)rowBase * HIDDEN;
    for (int i = threadIdx.x; i < n; i += 256) zb[i] = acc[i];
}

// ---------------- dense / quant kernels ------------------------------------

__global__ __launch_bounds__(256) void k_qd_gemm1(
    const float* __restrict__ feat, const float* __restrict__ noise,
    const float* __restrict__ W1, __half* __restrict__ y) {
    __shared__ float dqbuf[4][IN_DIM];
    const int lane = threadIdx.x & 63;
    const int wv = threadIdx.x >> 6;
    const int col = lane & 15;
    const int kg = lane >> 4;

    float w1r[32];
#pragma unroll
    for (int i = 0; i < 32; ++i) w1r[i] = W1[(kg * 32 + i) * HIDDEN + col];

    const int ngroups = N_NODES / 4;  // 25000
    for (int g = blockIdx.x; g < ngroups; g += gridDim.x) {
        const int node = g * 4 + wv;
        const float2 x = ((const float2*)(feat + (size_t)node * IN_DIM))[lane];
        const float2 nz = ((const float2*)(noise + (size_t)node * IN_DIM))[lane];
        float m = fminf(x.x, x.y), M = fmaxf(x.x, x.y);
#pragma unroll
        for (int off = 1; off < 64; off <<= 1) {
            m = fminf(m, __shfl_xor(m, off));
            M = fmaxf(M, __shfl_xor(M, off));
        }
        const float rscale = QMAXF / (M - m);
        const float inv = (M - m) / QMAXF;
        float2 dq;
        dq.x = qd_one(x.x, nz.x, m, rscale, inv);
        dq.y = qd_one(x.y, nz.y, m, rscale, inv);
        ((float2*)dqbuf[wv])[lane] = dq;
        __syncthreads();
        float acc = 0.0f;
        const float* dqk = dqbuf[wv] + kg * 32;
#pragma unroll
        for (int i = 0; i < 32; ++i) acc += dqk[i] * w1r[i];
        acc += __shfl_xor(acc, 16);
        acc += __shfl_xor(acc, 32);
        if (lane < 16) y[(size_t)node * HIDDEN + lane] = __float2half(acc);
        __syncthreads();
    }
}

__global__ __launch_bounds__(256) void k_qd_gemm16(
    const float* __restrict__ zin, const float* __restrict__ noise,
    const float* __restrict__ W2, __half* __restrict__ y) {
    __shared__ float w[HIDDEN * HIDDEN];
    w[threadIdx.x] = W2[threadIdx.x];
    __syncthreads();
    const int t = blockIdx.x * 256 + threadIdx.x;
    if (t >= N_NODES) return;
    float x[16], nz[16];
    {
        const float4* zr = (const float4*)(zin + (size_t)t * HIDDEN);
        const float4* nr = (const float4*)(noise + (size_t)t * HIDDEN);
#pragma unroll
        for (int i = 0; i < 4; ++i) {
            ((float4*)x)[i] = zr[i];
            ((float4*)nz)[i] = nr[i];
        }
    }
#pragma unroll
    for (int i = 0; i < 16; ++i) x[i] = fmaxf(x[i], 0.0f);
    float m = x[0], M = x[0];
#pragma unroll
    for (int i = 1; i < 16; ++i) { m = fminf(m, x[i]); M = fmaxf(M, x[i]); }
    const float rscale = QMAXF / (M - m);
    const float inv = (M - m) / QMAXF;
    float acc[16];
#pragma unroll
    for (int j = 0; j < 16; ++j) acc[j] = 0.0f;
#pragma unroll
    for (int k = 0; k < 16; ++k) {
        const float d = qd_one(x[k], nz[k], m, rscale, inv);
        const float4* wr = (const float4*)(w + k * 16);
#pragma unroll
        for (int j4 = 0; j4 < 4; ++j4) {
            float4 ww = wr[j4];
            acc[4 * j4 + 0] += d * ww.x;
            acc[4 * j4 + 1] += d * ww.y;
            acc[4 * j4 + 2] += d * ww.z;
            acc[4 * j4 + 3] += d * ww.w;
        }
    }
    __half hb[16];
#pragma unroll
    for (int i = 0; i < 16; ++i) hb[i] = __float2half(acc[i]);
    float4* yr = (float4*)(y + (size_t)t * HIDDEN);
    yr[0] = ((float4*)hb)[0];
    yr[1] = ((float4*)hb)[1];
}

__global__ __launch_bounds__(256) void k_qd16(
    const float* __restrict__ zin, const float* __restrict__ noise,
    __half* __restrict__ y) {
    const int t = blockIdx.x * 256 + threadIdx.x;
    if (t >= N_NODES) return;
    float x[16], nz[16];
    {
        const float4* zr = (const float4*)(zin + (size_t)t * HIDDEN);
        const float4* nr = (const float4*)(noise + (size_t)t * HIDDEN);
#pragma unroll
        for (int i = 0; i < 4; ++i) {
            ((float4*)x)[i] = zr[i];
            ((float4*)nz)[i] = nr[i];
        }
    }
#pragma unroll
    for (int i = 0; i < 16; ++i) x[i] = fmaxf(x[i], 0.0f);
    float m = x[0], M = x[0];
#pragma unroll
    for (int i = 1; i < 16; ++i) { m = fminf(m, x[i]); M = fmaxf(M, x[i]); }
    const float rscale = QMAXF / (M - m);
    const float inv = (M - m) / QMAXF;
    __half hb[16];
#pragma unroll
    for (int i = 0; i < 16; ++i)
        hb[i] = __float2half(qd_one(x[i], nz[i], m, rscale, inv));
    float4* yr = (float4*)(y + (size_t)t * HIDDEN);
    yr[0] = ((float4*)hb)[0];
    yr[1] = ((float4*)hb)[1];
}

__global__ __launch_bounds__(256) void k_gemm_out(
    const float* __restrict__ z, const float* __restrict__ W3,
    float* __restrict__ out) {
    __shared__ float w[HIDDEN * OUT_DIM];
    for (int i = threadIdx.x; i < HIDDEN * OUT_DIM; i += 256) w[i] = W3[i];
    __syncthreads();
    const int t = blockIdx.x * 256 + threadIdx.x;
    if (t >= N_NODES) return;
    float x[16];
    {
        const float4* zr = (const float4*)(z + (size_t)t * HIDDEN);
#pragma unroll
        for (int i = 0; i < 4; ++i) ((float4*)x)[i] = zr[i];
    }
    float acc[OUT_DIM];
#pragma unroll
    for (int j = 0; j < OUT_DIM; ++j) acc[j] = 0.0f;
#pragma unroll
    for (int k = 0; k < 16; ++k) {
        const float d = x[k];
        const float4* wr = (const float4*)(w + k * OUT_DIM);
#pragma unroll
        for (int j4 = 0; j4 < OUT_DIM / 4; ++j4) {
            float4 ww = wr[j4];
            acc[4 * j4 + 0] += d * ww.x;
            acc[4 * j4 + 1] += d * ww.y;
            acc[4 * j4 + 2] += d * ww.z;
            acc[4 * j4 + 3] += d * ww.w;
        }
    }
    float4* orow = (float4*)(out + (size_t)t * OUT_DIM);
#pragma unroll
    for (int i = 0; i < OUT_DIM / 4; ++i) orow[i] = ((float4*)acc)[i];
}

extern "C" void kernel_launch(void* const* d_in, const int* in_sizes, int n_in,
                              void* d_out, int out_size, void* d_ws,
                              size_t ws_size, hipStream_t stream) {
    const float* feat = (const float*)d_in[0];
    const int* row = (const int*)d_in[1];
    const int* col = (const int*)d_in[2];
    const float* vals = (const float*)d_in[3];
    const float* W1 = (const float*)d_in[4];
    const float* W2 = (const float*)d_in[5];
    const float* W3 = (const float*)d_in[6];
    const float* n1 = (const float*)d_in[7];
    const float* n2 = (const float*)d_in[8];
    const float* n3 = (const float*)d_in[9];
    float* out = (float*)d_out;

    // Workspace layout:
    __half* yh = (__half*)d_ws;                            // N*16 halfs (3.2 MB)
    float* z = (float*)(yh + (size_t)N_NODES * HIDDEN);    // N*16 floats (6.4 MB)
    int* cursor = (int*)(z + (size_t)N_NODES * HIDDEN);    // NB ints
    int2* es = (int2*)(cursor + NB);                       // NB*CAP int2 (16.8 MB)

    const int nodeBlocks = (N_NODES + 255) / 256;

    // --- bin edges once (reused by all 3 SpMMs) ---
    k_initcur<<<1, 512, 0, stream>>>(cursor);
    k_bin<<<NBLK_BIN, 256, 0, stream>>>(row, col, vals, cursor, es);

    // Layer 1: yh = qd(features) @ W1 ; z = A_graph @ yh
    k_qd_gemm1<<<2500, 256, 0, stream>>>(feat, n1, W1, yh);
    k_spmm_bin<<<NB_USED, 256, 0, stream>>>(cursor, es, yh, z);

    // Layer 2
    k_qd_gemm16<<<nodeBlocks, 256, 0, stream>>>(z, n2, W2, yh);
    k_spmm_bin<<<NB_USED, 256, 0, stream>>>(cursor, es, yh, z);

    // Layer 3
    k_qd16<<<nodeBlocks, 256, 0, stream>>>(z, n3, yh);
    k_spmm_bin<<<NB_USED, 256, 0, stream>>>(cursor, es, yh, z);
    k_gemm_out<<<nodeBlocks, 256, 0, stream>>>(z, W3, out);
}